// Round 1
// baseline (15874.651 us; speedup 1.0000x reference)
//
#include <hip/hip_runtime.h>

// Fused SpikingDenseLayer: B=256, T=100, F=K=1024, U=1024.
// One block = one (batch b, 128-wide u-tile), 256 threads.
// v2 changes vs baseline:
//  * micro-tile remap: tg = tid>>4, t = i*16+tg  -> pad rows (t>=100) are
//    wave-uniform: waves 1-3 do i=0..5 only, wave 0 adds t=96..99.
//    10.7% fewer FMAs issued.
//  * staging via global_load_lds (width 16) into LINEAR As[100][16] and
//    Ws[16][128] -- no transpose, no ds_writes, no VGPR round-trip.
//    Under the remap, a-reads (ds_read_b64) and b-reads (ds_read_b128,
//    u-columns split into halves u and u+64) are 2-way-bank = free.
//  * LIF scan chunked 2x50 rows -> LDS 26.4 KB -> 5-6 blocks/CU
//    (vs 3 before), __launch_bounds__(256,5).
// Per-output FMA chain remains strictly k-ascending -> currents bitwise
// identical to the previously-passing kernel; scan math unchanged.

#define UN 128              // u-columns per block
#define BK 16               // k-slice staged per iteration
#define CS 132              // Cs row stride in floats (128 + 4)
#define CHUNK 50            // t-rows per scan chunk
#define TMAX 100

__device__ __forceinline__ void gload_lds16(const float* g, float* l) {
    __builtin_amdgcn_global_load_lds(
        (const __attribute__((address_space(1))) void*)g,
        (__attribute__((address_space(3))) void*)l,
        16, 0, 0);
}

__global__ __launch_bounds__(256, 5) void fused_snn(
    const float* __restrict__ x,     // [B,T,F]
    const float* __restrict__ W,     // [F,U]
    const float* __restrict__ bias,  // [U]
    float* __restrict__ spikes,      // [B,T,U]
    float* __restrict__ counts,      // [B,U]
    int B, int T, int F, int U)
{
    // Union: staging (As[100][16]=1600 + Ws[16][128]=2048 floats) lives at
    // the front; after the K-loop the region is reused as Cs[50][132].
    __shared__ __align__(16) float smem[CHUNK * CS];   // 6600 floats = 26.4 KB
    float* As = smem;            // [100][16]  linear, no pad
    float* Ws = smem + 1600;     // [16][128]  linear, no pad

    const int tid = threadIdx.x;
    const int tg  = tid >> 4;    // 0..15 -> t = i*16 + tg
    const int ug  = tid & 15;    // 0..15 -> u cols {4ug..4ug+3} and {64+4ug..}
    const int u0  = blockIdx.x * UN;
    const int b   = blockIdx.y;

    float acc[7][8];
    #pragma unroll
    for (int i = 0; i < 7; i++)
        #pragma unroll
        for (int j = 0; j < 8; j++) acc[i][j] = 0.f;

    const float* xb = x + (size_t)b * T * F;

    // Staging addresses. A tile: 100 rows x 64 B = 400 16-B slots; slot s:
    // row s>>2, byte off (s&3)*16. W tile: 16 rows x 512 B = 512 slots;
    // slot s: krow s>>5, byte off (s&31)*16. LDS dest = slot*16 (linear,
    // wave-uniform base + lane*16 as global_load_lds requires).
    const float* ga0 = xb + (size_t)(tid >> 2) * F + (tid & 3) * 4;
    const float* ga1 = xb + (size_t)(64 + (tid >> 2)) * F + (tid & 3) * 4;
    const float* gw0 = W + (size_t)(tid >> 5) * U + u0 + (tid & 31) * 4;
    const float* gw1 = W + (size_t)(8 + (tid >> 5)) * U + u0 + (tid & 31) * 4;
    float* la0 = As + tid * 4;
    float* la1 = As + (256 + tid) * 4;
    float* lw0 = Ws + tid * 4;
    float* lw1 = Ws + (256 + tid) * 4;
    const bool a1on = (tid < 144);           // slots 256..399
    const bool w0   = (tid < 64);            // wave 0: owns tail rows 96..99

    for (int k0 = 0; k0 < F; k0 += BK) {
        gload_lds16(ga0 + k0, la0);
        if (a1on) gload_lds16(ga1 + k0, la1);
        gload_lds16(gw0 + (size_t)k0 * U, lw0);
        gload_lds16(gw1 + (size_t)k0 * U, lw1);
        __syncthreads();   // vmcnt(0) drain: staged tile visible to all

        const float* ap = As + tg * 16;      // row t=i*16+tg at +i*256+kk
        const float* wp = Ws + ug * 4;
        #pragma unroll
        for (int kk = 0; kk < BK; kk += 2) {
            float2 a2[6];
            #pragma unroll
            for (int i = 0; i < 6; i++)
                a2[i] = *(const float2*)(ap + i * 256 + kk);
            #pragma unroll
            for (int p = 0; p < 2; p++) {
                float4 b0 = *(const float4*)(wp + (kk + p) * 128);
                float4 b1 = *(const float4*)(wp + (kk + p) * 128 + 64);
                #pragma unroll
                for (int i = 0; i < 6; i++) {
                    const float a = p ? a2[i].y : a2[i].x;
                    acc[i][0] += a * b0.x;  acc[i][1] += a * b0.y;
                    acc[i][2] += a * b0.z;  acc[i][3] += a * b0.w;
                    acc[i][4] += a * b1.x;  acc[i][5] += a * b1.y;
                    acc[i][6] += a * b1.z;  acc[i][7] += a * b1.w;
                }
            }
        }
        // tail rows t=96..99: wave-uniform branch, wave 0 only (tg 0..3)
        if (w0) {
            #pragma unroll
            for (int kk = 0; kk < BK; kk += 2) {
                float2 a6 = *(const float2*)(ap + 6 * 256 + kk);
                #pragma unroll
                for (int p = 0; p < 2; p++) {
                    float4 b0 = *(const float4*)(wp + (kk + p) * 128);
                    float4 b1 = *(const float4*)(wp + (kk + p) * 128 + 64);
                    const float a = p ? a6.y : a6.x;
                    acc[6][0] += a * b0.x;  acc[6][1] += a * b0.y;
                    acc[6][2] += a * b0.z;  acc[6][3] += a * b0.w;
                    acc[6][4] += a * b1.x;  acc[6][5] += a * b1.y;
                    acc[6][6] += a * b1.z;  acc[6][7] += a * b1.w;
                }
            }
        }
        __syncthreads();   // all reads done before next stage / Cs overwrite
    }

    // ---- bias ----
    float bb[8];
    {
        float4 bv0 = *(const float4*)(bias + u0 + 4 * ug);
        float4 bv1 = *(const float4*)(bias + u0 + 64 + 4 * ug);
        bb[0] = bv0.x; bb[1] = bv0.y; bb[2] = bv0.z; bb[3] = bv0.w;
        bb[4] = bv1.x; bb[5] = bv1.y; bb[6] = bv1.z; bb[7] = bv1.w;
    }

    // ---- chunked dump + LIF scan (2 x 50 t-rows) ----
    float v = 0.f, cnt = 0.f;
    float* sp = spikes + (size_t)b * T * U + u0 + tid;   // used when tid<UN

    #pragma unroll
    for (int c = 0; c < 2; c++) {
        #pragma unroll
        for (int i = 0; i < 7; i++) {
            const int t = i * 16 + tg;
            if (t >= c * CHUNK && t < c * CHUNK + CHUNK && t < TMAX) {
                const int r = t - c * CHUNK;
                float4 c0, c1;
                c0.x = acc[i][0] + bb[0]; c0.y = acc[i][1] + bb[1];
                c0.z = acc[i][2] + bb[2]; c0.w = acc[i][3] + bb[3];
                c1.x = acc[i][4] + bb[4]; c1.y = acc[i][5] + bb[5];
                c1.z = acc[i][6] + bb[6]; c1.w = acc[i][7] + bb[7];
                *(float4*)(smem + r * CS + 4 * ug)      = c0;
                *(float4*)(smem + r * CS + 64 + 4 * ug) = c1;
            }
        }
        __syncthreads();
        if (tid < UN) {
#pragma clang fp contract(off)
            // rounding matches numpy elementwise exactly:
            // v = 0.25*v + round(0.75*c); spike = v > 1.0; v -= spike.
            for (int r = 0; r < CHUNK; r++) {
                float cval = smem[r * CS + tid];
                v = 0.25f * v + 0.75f * cval;
                float s = (v > 1.0f) ? 1.0f : 0.0f;
                v -= s;
                cnt += s;
                sp[(size_t)(c * CHUNK + r) * U] = s;
            }
        }
        __syncthreads();   // scan done before chunk 1 overwrites Cs
    }
    if (tid < UN) counts[(size_t)b * U + u0 + tid] = cnt;
}

extern "C" void kernel_launch(void* const* d_in, const int* in_sizes, int n_in,
                              void* d_out, int out_size, void* d_ws, size_t ws_size,
                              hipStream_t stream) {
    const float* x    = (const float*)d_in[0];  // [B,T,F]
    const float* kern = (const float*)d_in[1];  // [F,U]
    const float* bias = (const float*)d_in[2];  // [U]
    float* out = (float*)d_out;

    const int U = in_sizes[2];                 // 1024
    const int F = in_sizes[1] / U;             // 1024
    const int R = in_sizes[0] / F;             // B*T = 25600
    const int B = out_size / U - R;            // 256
    const int T = R / B;                       // 100

    float* spikes = out;
    float* counts = out + (size_t)R * U;

    dim3 grid(U / UN, B);                      // (8, 256)
    fused_snn<<<grid, 256, 0, stream>>>(x, kern, bias, spikes, counts,
                                        B, T, F, U);
}

// Round 2
// 9687.579 us; speedup vs baseline: 1.6387x; 1.6387x over previous
//
#include <hip/hip_runtime.h>

// Fused SpikingDenseLayer: B=256, T=100, F=K=1024, U=1024.
// One block = one (batch b, 128-wide u-tile), 256 threads.
// v3 = v2 with the register-spill fixed:
//  * __launch_bounds__(256, 4): v2's (256,5) capped VGPRs below the 56-reg
//    accumulator -> acc spilled to scratch (VGPR_Count=48, 55 GB/dispatch of
//    scratch traffic, 18x regression). Cap 128 regs leaves ~100-reg kernel
//    unspilled; LDS 26.6 KB still allows it, occupancy 16 waves/CU (50%).
//  * micro-tile remap: tg = tid>>4, t = i*16+tg -> pad rows wave-uniform,
//    10.7% fewer FMAs than baseline.
//  * staging via global_load_lds (width 16) into LINEAR As[100][16] and
//    Ws[16][128]; v2 proved this is bank-conflict-free (counter = 0).
//  * LIF scan chunked 2x50 rows -> LDS 26.4 KB.
// Per-output FMA chain strictly k-ascending -> currents bitwise identical.

#define UN 128              // u-columns per block
#define BK 16               // k-slice staged per iteration
#define CS 132              // Cs row stride in floats (128 + 4)
#define CHUNK 50            // t-rows per scan chunk
#define TMAX 100

__device__ __forceinline__ void gload_lds16(const float* g, float* l) {
    __builtin_amdgcn_global_load_lds(
        (const __attribute__((address_space(1))) void*)g,
        (__attribute__((address_space(3))) void*)l,
        16, 0, 0);
}

__global__ __launch_bounds__(256, 4) void fused_snn(
    const float* __restrict__ x,     // [B,T,F]
    const float* __restrict__ W,     // [F,U]
    const float* __restrict__ bias,  // [U]
    float* __restrict__ spikes,      // [B,T,U]
    float* __restrict__ counts,      // [B,U]
    int B, int T, int F, int U)
{
    // Union: staging (As[100][16]=1600 + Ws[16][128]=2048 floats) lives at
    // the front; after the K-loop the region is reused as Cs[50][132].
    __shared__ __align__(16) float smem[CHUNK * CS];   // 6600 floats = 26.4 KB
    float* As = smem;            // [100][16]  linear, no pad
    float* Ws = smem + 1600;     // [16][128]  linear, no pad

    const int tid = threadIdx.x;
    const int tg  = tid >> 4;    // 0..15 -> t = i*16 + tg
    const int ug  = tid & 15;    // 0..15 -> u cols {4ug..4ug+3} and {64+4ug..}
    const int u0  = blockIdx.x * UN;
    const int b   = blockIdx.y;

    float acc[7][8];
    #pragma unroll
    for (int i = 0; i < 7; i++)
        #pragma unroll
        for (int j = 0; j < 8; j++) acc[i][j] = 0.f;

    const float* xb = x + (size_t)b * T * F;

    // Staging addresses. A tile: 100 rows x 64 B = 400 16-B slots; slot s:
    // row s>>2, byte off (s&3)*16. W tile: 16 rows x 512 B = 512 slots;
    // slot s: krow s>>5, byte off (s&31)*16. LDS dest = slot*16 (linear,
    // wave-uniform base + lane*16 as global_load_lds requires).
    const float* ga0 = xb + (size_t)(tid >> 2) * F + (tid & 3) * 4;
    const float* ga1 = xb + (size_t)(64 + (tid >> 2)) * F + (tid & 3) * 4;
    const float* gw0 = W + (size_t)(tid >> 5) * U + u0 + (tid & 31) * 4;
    const float* gw1 = W + (size_t)(8 + (tid >> 5)) * U + u0 + (tid & 31) * 4;
    float* la0 = As + tid * 4;
    float* la1 = As + (256 + tid) * 4;
    float* lw0 = Ws + tid * 4;
    float* lw1 = Ws + (256 + tid) * 4;
    const bool a1on = (tid < 144);           // slots 256..399
    const bool w0   = (tid < 64);            // wave 0: owns tail rows 96..99

    for (int k0 = 0; k0 < F; k0 += BK) {
        gload_lds16(ga0 + k0, la0);
        if (a1on) gload_lds16(ga1 + k0, la1);
        gload_lds16(gw0 + (size_t)k0 * U, lw0);
        gload_lds16(gw1 + (size_t)k0 * U, lw1);
        __syncthreads();   // vmcnt(0) drain: staged tile visible to all

        const float* ap = As + tg * 16;      // row t=i*16+tg at +i*256+kk
        const float* wp = Ws + ug * 4;
        #pragma unroll
        for (int kk = 0; kk < BK; kk += 2) {
            float2 a2[6];
            #pragma unroll
            for (int i = 0; i < 6; i++)
                a2[i] = *(const float2*)(ap + i * 256 + kk);
            #pragma unroll
            for (int p = 0; p < 2; p++) {
                float4 b0 = *(const float4*)(wp + (kk + p) * 128);
                float4 b1 = *(const float4*)(wp + (kk + p) * 128 + 64);
                #pragma unroll
                for (int i = 0; i < 6; i++) {
                    const float a = p ? a2[i].y : a2[i].x;
                    acc[i][0] += a * b0.x;  acc[i][1] += a * b0.y;
                    acc[i][2] += a * b0.z;  acc[i][3] += a * b0.w;
                    acc[i][4] += a * b1.x;  acc[i][5] += a * b1.y;
                    acc[i][6] += a * b1.z;  acc[i][7] += a * b1.w;
                }
            }
        }
        // tail rows t=96..99: wave-uniform branch, wave 0 only (tg 0..3)
        if (w0) {
            #pragma unroll
            for (int kk = 0; kk < BK; kk += 2) {
                float2 a6 = *(const float2*)(ap + 6 * 256 + kk);
                #pragma unroll
                for (int p = 0; p < 2; p++) {
                    float4 b0 = *(const float4*)(wp + (kk + p) * 128);
                    float4 b1 = *(const float4*)(wp + (kk + p) * 128 + 64);
                    const float a = p ? a6.y : a6.x;
                    acc[6][0] += a * b0.x;  acc[6][1] += a * b0.y;
                    acc[6][2] += a * b0.z;  acc[6][3] += a * b0.w;
                    acc[6][4] += a * b1.x;  acc[6][5] += a * b1.y;
                    acc[6][6] += a * b1.z;  acc[6][7] += a * b1.w;
                }
            }
        }
        __syncthreads();   // all reads done before next stage / Cs overwrite
    }

    // ---- bias ----
    float bb[8];
    {
        float4 bv0 = *(const float4*)(bias + u0 + 4 * ug);
        float4 bv1 = *(const float4*)(bias + u0 + 64 + 4 * ug);
        bb[0] = bv0.x; bb[1] = bv0.y; bb[2] = bv0.z; bb[3] = bv0.w;
        bb[4] = bv1.x; bb[5] = bv1.y; bb[6] = bv1.z; bb[7] = bv1.w;
    }

    // ---- chunked dump + LIF scan (2 x 50 t-rows) ----
    float v = 0.f, cnt = 0.f;
    float* sp = spikes + (size_t)b * T * U + u0 + tid;   // used when tid<UN

    #pragma unroll
    for (int c = 0; c < 2; c++) {
        #pragma unroll
        for (int i = 0; i < 7; i++) {
            const int t = i * 16 + tg;
            if (t >= c * CHUNK && t < c * CHUNK + CHUNK && t < TMAX) {
                const int r = t - c * CHUNK;
                float4 c0, c1;
                c0.x = acc[i][0] + bb[0]; c0.y = acc[i][1] + bb[1];
                c0.z = acc[i][2] + bb[2]; c0.w = acc[i][3] + bb[3];
                c1.x = acc[i][4] + bb[4]; c1.y = acc[i][5] + bb[5];
                c1.z = acc[i][6] + bb[6]; c1.w = acc[i][7] + bb[7];
                *(float4*)(smem + r * CS + 4 * ug)      = c0;
                *(float4*)(smem + r * CS + 64 + 4 * ug) = c1;
            }
        }
        __syncthreads();
        if (tid < UN) {
#pragma clang fp contract(off)
            // rounding matches numpy elementwise exactly:
            // v = 0.25*v + round(0.75*c); spike = v > 1.0; v -= spike.
            for (int r = 0; r < CHUNK; r++) {
                float cval = smem[r * CS + tid];
                v = 0.25f * v + 0.75f * cval;
                float s = (v > 1.0f) ? 1.0f : 0.0f;
                v -= s;
                cnt += s;
                sp[(size_t)(c * CHUNK + r) * U] = s;
            }
        }
        __syncthreads();   // scan done before chunk 1 overwrites Cs
    }
    if (tid < UN) counts[(size_t)b * U + u0 + tid] = cnt;
}

extern "C" void kernel_launch(void* const* d_in, const int* in_sizes, int n_in,
                              void* d_out, int out_size, void* d_ws, size_t ws_size,
                              hipStream_t stream) {
    const float* x    = (const float*)d_in[0];  // [B,T,F]
    const float* kern = (const float*)d_in[1];  // [F,U]
    const float* bias = (const float*)d_in[2];  // [U]
    float* out = (float*)d_out;

    const int U = in_sizes[2];                 // 1024
    const int F = in_sizes[1] / U;             // 1024
    const int R = in_sizes[0] / F;             // B*T = 25600
    const int B = out_size / U - R;            // 256
    const int T = R / B;                       // 100

    float* spikes = out;
    float* counts = out + (size_t)R * U;

    dim3 grid(U / UN, B);                      // (8, 256)
    fused_snn<<<grid, 256, 0, stream>>>(x, kern, bias, spikes, counts,
                                        B, T, F, U);
}

// Round 3
// 2689.428 us; speedup vs baseline: 5.9026x; 3.6021x over previous
//
#include <hip/hip_runtime.h>

// Fused SpikingDenseLayer: B=256, T=100, F=K=1024, U=1024.
// One block = one (batch b, 128-wide u-tile), 256 threads.
// v4 = v3 with the spill ACTUALLY fixed:
//  * empirical hipcc rule on gfx950: VGPR cap ~= 256/min_waves_arg
//    (arg 3->84, 4->64, 5->48 measured). Kernel needs ~100 live VGPRs
//    (acc[7][8]=56 + staging addrs + fma temps), so arg must be <=2.
//    __launch_bounds__(256,2) -> cap 128 -> no spill; actual alloc ~100
//    still gives 16 waves/CU (50% occupancy) since <=128-reg step.
//  * micro-tile remap: tg = tid>>4, t = i*16+tg -> pad rows wave-uniform,
//    10.7% fewer FMAs than baseline.
//  * staging via global_load_lds (width 16) into LINEAR As[100][16] and
//    Ws[16][128]; proven bank-conflict-free (counter = 0 in v2 and v3).
//  * LIF scan chunked 2x50 rows -> LDS 26.4 KB.
// Per-output FMA chain strictly k-ascending -> currents bitwise identical.

#define UN 128              // u-columns per block
#define BK 16               // k-slice staged per iteration
#define CS 132              // Cs row stride in floats (128 + 4)
#define CHUNK 50            // t-rows per scan chunk
#define TMAX 100

__device__ __forceinline__ void gload_lds16(const float* g, float* l) {
    __builtin_amdgcn_global_load_lds(
        (const __attribute__((address_space(1))) void*)g,
        (__attribute__((address_space(3))) void*)l,
        16, 0, 0);
}

__global__ __launch_bounds__(256, 2) void fused_snn(
    const float* __restrict__ x,     // [B,T,F]
    const float* __restrict__ W,     // [F,U]
    const float* __restrict__ bias,  // [U]
    float* __restrict__ spikes,      // [B,T,U]
    float* __restrict__ counts,      // [B,U]
    int B, int T, int F, int U)
{
    // Union: staging (As[100][16]=1600 + Ws[16][128]=2048 floats) lives at
    // the front; after the K-loop the region is reused as Cs[50][132].
    __shared__ __align__(16) float smem[CHUNK * CS];   // 6600 floats = 26.4 KB
    float* As = smem;            // [100][16]  linear, no pad
    float* Ws = smem + 1600;     // [16][128]  linear, no pad

    const int tid = threadIdx.x;
    const int tg  = tid >> 4;    // 0..15 -> t = i*16 + tg
    const int ug  = tid & 15;    // 0..15 -> u cols {4ug..4ug+3} and {64+4ug..}
    const int u0  = blockIdx.x * UN;
    const int b   = blockIdx.y;

    float acc[7][8];
    #pragma unroll
    for (int i = 0; i < 7; i++)
        #pragma unroll
        for (int j = 0; j < 8; j++) acc[i][j] = 0.f;

    const float* xb = x + (size_t)b * T * F;

    // Staging addresses. A tile: 100 rows x 64 B = 400 16-B slots; slot s:
    // row s>>2, byte off (s&3)*16. W tile: 16 rows x 512 B = 512 slots;
    // slot s: krow s>>5, byte off (s&31)*16. LDS dest = slot*16 (linear,
    // wave-uniform base + lane*16 as global_load_lds requires).
    const float* ga0 = xb + (size_t)(tid >> 2) * F + (tid & 3) * 4;
    const float* ga1 = xb + (size_t)(64 + (tid >> 2)) * F + (tid & 3) * 4;
    const float* gw0 = W + (size_t)(tid >> 5) * U + u0 + (tid & 31) * 4;
    const float* gw1 = W + (size_t)(8 + (tid >> 5)) * U + u0 + (tid & 31) * 4;
    float* la0 = As + tid * 4;
    float* la1 = As + (256 + tid) * 4;
    float* lw0 = Ws + tid * 4;
    float* lw1 = Ws + (256 + tid) * 4;
    const bool a1on = (tid < 144);           // slots 256..399
    const bool w0   = (tid < 64);            // wave 0: owns tail rows 96..99

    for (int k0 = 0; k0 < F; k0 += BK) {
        gload_lds16(ga0 + k0, la0);
        if (a1on) gload_lds16(ga1 + k0, la1);
        gload_lds16(gw0 + (size_t)k0 * U, lw0);
        gload_lds16(gw1 + (size_t)k0 * U, lw1);
        __syncthreads();   // vmcnt(0) drain: staged tile visible to all

        const float* ap = As + tg * 16;      // row t=i*16+tg at +i*256+kk
        const float* wp = Ws + ug * 4;
        #pragma unroll
        for (int kk = 0; kk < BK; kk += 2) {
            float2 a2[6];
            #pragma unroll
            for (int i = 0; i < 6; i++)
                a2[i] = *(const float2*)(ap + i * 256 + kk);
            #pragma unroll
            for (int p = 0; p < 2; p++) {
                float4 b0 = *(const float4*)(wp + (kk + p) * 128);
                float4 b1 = *(const float4*)(wp + (kk + p) * 128 + 64);
                #pragma unroll
                for (int i = 0; i < 6; i++) {
                    const float a = p ? a2[i].y : a2[i].x;
                    acc[i][0] += a * b0.x;  acc[i][1] += a * b0.y;
                    acc[i][2] += a * b0.z;  acc[i][3] += a * b0.w;
                    acc[i][4] += a * b1.x;  acc[i][5] += a * b1.y;
                    acc[i][6] += a * b1.z;  acc[i][7] += a * b1.w;
                }
            }
        }
        // tail rows t=96..99: wave-uniform branch, wave 0 only (tg 0..3)
        if (w0) {
            #pragma unroll
            for (int kk = 0; kk < BK; kk += 2) {
                float2 a6 = *(const float2*)(ap + 6 * 256 + kk);
                #pragma unroll
                for (int p = 0; p < 2; p++) {
                    float4 b0 = *(const float4*)(wp + (kk + p) * 128);
                    float4 b1 = *(const float4*)(wp + (kk + p) * 128 + 64);
                    const float a = p ? a6.y : a6.x;
                    acc[6][0] += a * b0.x;  acc[6][1] += a * b0.y;
                    acc[6][2] += a * b0.z;  acc[6][3] += a * b0.w;
                    acc[6][4] += a * b1.x;  acc[6][5] += a * b1.y;
                    acc[6][6] += a * b1.z;  acc[6][7] += a * b1.w;
                }
            }
        }
        __syncthreads();   // all reads done before next stage / Cs overwrite
    }

    // ---- bias ----
    float bb[8];
    {
        float4 bv0 = *(const float4*)(bias + u0 + 4 * ug);
        float4 bv1 = *(const float4*)(bias + u0 + 64 + 4 * ug);
        bb[0] = bv0.x; bb[1] = bv0.y; bb[2] = bv0.z; bb[3] = bv0.w;
        bb[4] = bv1.x; bb[5] = bv1.y; bb[6] = bv1.z; bb[7] = bv1.w;
    }

    // ---- chunked dump + LIF scan (2 x 50 t-rows) ----
    float v = 0.f, cnt = 0.f;
    float* sp = spikes + (size_t)b * T * U + u0 + tid;   // used when tid<UN

    #pragma unroll
    for (int c = 0; c < 2; c++) {
        #pragma unroll
        for (int i = 0; i < 7; i++) {
            const int t = i * 16 + tg;
            if (t >= c * CHUNK && t < c * CHUNK + CHUNK && t < TMAX) {
                const int r = t - c * CHUNK;
                float4 c0, c1;
                c0.x = acc[i][0] + bb[0]; c0.y = acc[i][1] + bb[1];
                c0.z = acc[i][2] + bb[2]; c0.w = acc[i][3] + bb[3];
                c1.x = acc[i][4] + bb[4]; c1.y = acc[i][5] + bb[5];
                c1.z = acc[i][6] + bb[6]; c1.w = acc[i][7] + bb[7];
                *(float4*)(smem + r * CS + 4 * ug)      = c0;
                *(float4*)(smem + r * CS + 64 + 4 * ug) = c1;
            }
        }
        __syncthreads();
        if (tid < UN) {
#pragma clang fp contract(off)
            // rounding matches numpy elementwise exactly:
            // v = 0.25*v + round(0.75*c); spike = v > 1.0; v -= spike.
            for (int r = 0; r < CHUNK; r++) {
                float cval = smem[r * CS + tid];
                v = 0.25f * v + 0.75f * cval;
                float s = (v > 1.0f) ? 1.0f : 0.0f;
                v -= s;
                cnt += s;
                sp[(size_t)(c * CHUNK + r) * U] = s;
            }
        }
        __syncthreads();   // scan done before chunk 1 overwrites Cs
    }
    if (tid < UN) counts[(size_t)b * U + u0 + tid] = cnt;
}

extern "C" void kernel_launch(void* const* d_in, const int* in_sizes, int n_in,
                              void* d_out, int out_size, void* d_ws, size_t ws_size,
                              hipStream_t stream) {
    const float* x    = (const float*)d_in[0];  // [B,T,F]
    const float* kern = (const float*)d_in[1];  // [F,U]
    const float* bias = (const float*)d_in[2];  // [U]
    float* out = (float*)d_out;

    const int U = in_sizes[2];                 // 1024
    const int F = in_sizes[1] / U;             // 1024
    const int R = in_sizes[0] / F;             // B*T = 25600
    const int B = out_size / U - R;            // 256
    const int T = R / B;                       // 100

    float* spikes = out;
    float* counts = out + (size_t)R * U;

    dim3 grid(U / UN, B);                      // (8, 256)
    fused_snn<<<grid, 256, 0, stream>>>(x, kern, bias, spikes, counts,
                                        B, T, F, U);
}

// Round 4
// 735.860 us; speedup vs baseline: 21.5729x; 3.6548x over previous
//
#include <hip/hip_runtime.h>

// Fused SpikingDenseLayer: B=256, T=100, F=K=1024, U=1024.
// One block = one (batch b, 128-wide u-tile), 256 threads.
// v5 = v4 with register demand fixed STRUCTURALLY:
//  * kk loop is ROLLED (#pragma unroll 1). v4 fully unrolled it and hipcc
//    hoisted all 8 iterations' ds_reads (~160 load temps) on top of the
//    56-reg accumulator -> demand > any usable cap -> spill at VGPR=128
//    (WRITE_SIZE 6.9 GB vs 0.11 GB ideal). Rolled body keeps ~100 live.
//  * __launch_bounds__(256) with NO min-waves arg: measured hipcc rule is
//    cap ~= 256/arg (84/64/48/128 at arg 3/4/5/2) -> any arg >= 2 can
//    re-spill. Let the allocator take what it needs; zero spill dominates
//    occupancy on this kernel (848 us at 31% occ vs 2689 us spilling).
//  * tail rows t=96..99 are a wave-uniform if(w0) block INSIDE the rolled
//    loop: wave 0 issues 112 FMAs/iter all-lanes-active, waves 1-3 issue
//    96. No masked-lane waste, 10.7% fewer FMAs than baseline.
//  * staging via global_load_lds (width 16) into LINEAR As[100][16] and
//    Ws[16][128]; bank-conflict counter = 0 across v2/v3/v4.
//  * LIF scan chunked 2x50 rows -> LDS 26.4 KB.
// Per-output FMA chain strictly k-ascending -> currents bitwise identical.

#define UN 128              // u-columns per block
#define BK 16               // k-slice staged per iteration
#define CS 132              // Cs row stride in floats (128 + 4)
#define CHUNK 50            // t-rows per scan chunk
#define TMAX 100

__device__ __forceinline__ void gload_lds16(const float* g, float* l) {
    __builtin_amdgcn_global_load_lds(
        (const __attribute__((address_space(1))) void*)g,
        (__attribute__((address_space(3))) void*)l,
        16, 0, 0);
}

__global__ __launch_bounds__(256) void fused_snn(
    const float* __restrict__ x,     // [B,T,F]
    const float* __restrict__ W,     // [F,U]
    const float* __restrict__ bias,  // [U]
    float* __restrict__ spikes,      // [B,T,U]
    float* __restrict__ counts,      // [B,U]
    int B, int T, int F, int U)
{
    // Union: staging (As[100][16]=1600 + Ws[16][128]=2048 floats) lives at
    // the front; after the K-loop the region is reused as Cs[50][132].
    __shared__ __align__(16) float smem[CHUNK * CS];   // 6600 floats = 26.4 KB
    float* As = smem;            // [100][16]  linear, no pad
    float* Ws = smem + 1600;     // [16][128]  linear, no pad

    const int tid = threadIdx.x;
    const int tg  = tid >> 4;    // 0..15 -> t = i*16 + tg
    const int ug  = tid & 15;    // 0..15 -> u cols {4ug..4ug+3} and {64+4ug..}
    const int u0  = blockIdx.x * UN;
    const int b   = blockIdx.y;

    float acc[7][8];
    #pragma unroll
    for (int i = 0; i < 7; i++)
        #pragma unroll
        for (int j = 0; j < 8; j++) acc[i][j] = 0.f;

    const float* xb = x + (size_t)b * T * F;

    // Staging addresses. A tile: 100 rows x 64 B = 400 16-B slots; slot s:
    // row s>>2, byte off (s&3)*16. W tile: 16 rows x 512 B = 512 slots;
    // slot s: krow s>>5, byte off (s&31)*16. LDS dest = slot*16 (linear,
    // wave-uniform base + lane*16 as global_load_lds requires).
    const float* ga0 = xb + (size_t)(tid >> 2) * F + (tid & 3) * 4;
    const float* ga1 = xb + (size_t)(64 + (tid >> 2)) * F + (tid & 3) * 4;
    const float* gw0 = W + (size_t)(tid >> 5) * U + u0 + (tid & 31) * 4;
    const float* gw1 = W + (size_t)(8 + (tid >> 5)) * U + u0 + (tid & 31) * 4;
    float* la0 = As + tid * 4;
    float* la1 = As + (256 + tid) * 4;
    float* lw0 = Ws + tid * 4;
    float* lw1 = Ws + (256 + tid) * 4;
    const bool a1on = (tid < 144);           // slots 256..399
    const bool w0   = (tid < 64);            // wave 0: owns tail rows 96..99

    for (int k0 = 0; k0 < F; k0 += BK) {
        gload_lds16(ga0 + k0, la0);
        if (a1on) gload_lds16(ga1 + k0, la1);
        gload_lds16(gw0 + (size_t)k0 * U, lw0);
        gload_lds16(gw1 + (size_t)k0 * U, lw1);
        __syncthreads();   // vmcnt(0) drain: staged tile visible to all

        const float* ap = As + tg * 16;      // row t=i*16+tg at +i*256+kk
        const float* wp = Ws + ug * 4;
        #pragma unroll 1
        for (int kk = 0; kk < BK; kk += 2) {
            // b-rows for k=kk (b0,b1) and k=kk+1 (b2,b3); u-halves 0 and 64.
            float4 b0 = *(const float4*)(wp + kk * 128);
            float4 b1 = *(const float4*)(wp + kk * 128 + 64);
            float4 b2 = *(const float4*)(wp + kk * 128 + 128);
            float4 b3 = *(const float4*)(wp + kk * 128 + 192);
            #pragma unroll
            for (int i = 0; i < 6; i++) {
                float2 a = *(const float2*)(ap + i * 256 + kk);
                acc[i][0] += a.x * b0.x;  acc[i][1] += a.x * b0.y;
                acc[i][2] += a.x * b0.z;  acc[i][3] += a.x * b0.w;
                acc[i][4] += a.x * b1.x;  acc[i][5] += a.x * b1.y;
                acc[i][6] += a.x * b1.z;  acc[i][7] += a.x * b1.w;
                acc[i][0] += a.y * b2.x;  acc[i][1] += a.y * b2.y;
                acc[i][2] += a.y * b2.z;  acc[i][3] += a.y * b2.w;
                acc[i][4] += a.y * b3.x;  acc[i][5] += a.y * b3.y;
                acc[i][6] += a.y * b3.z;  acc[i][7] += a.y * b3.w;
            }
            if (w0) {   // tail rows t=96..99, wave-uniform, all lanes active
                float2 a = *(const float2*)(ap + 6 * 256 + kk);
                acc[6][0] += a.x * b0.x;  acc[6][1] += a.x * b0.y;
                acc[6][2] += a.x * b0.z;  acc[6][3] += a.x * b0.w;
                acc[6][4] += a.x * b1.x;  acc[6][5] += a.x * b1.y;
                acc[6][6] += a.x * b1.z;  acc[6][7] += a.x * b1.w;
                acc[6][0] += a.y * b2.x;  acc[6][1] += a.y * b2.y;
                acc[6][2] += a.y * b2.z;  acc[6][3] += a.y * b2.w;
                acc[6][4] += a.y * b3.x;  acc[6][5] += a.y * b3.y;
                acc[6][6] += a.y * b3.z;  acc[6][7] += a.y * b3.w;
            }
        }
        __syncthreads();   // all reads done before next stage / Cs overwrite
    }

    // ---- bias ----
    float bb[8];
    {
        float4 bv0 = *(const float4*)(bias + u0 + 4 * ug);
        float4 bv1 = *(const float4*)(bias + u0 + 64 + 4 * ug);
        bb[0] = bv0.x; bb[1] = bv0.y; bb[2] = bv0.z; bb[3] = bv0.w;
        bb[4] = bv1.x; bb[5] = bv1.y; bb[6] = bv1.z; bb[7] = bv1.w;
    }

    // ---- chunked dump + LIF scan (2 x 50 t-rows) ----
    float v = 0.f, cnt = 0.f;
    float* sp = spikes + (size_t)b * T * U + u0 + tid;   // used when tid<UN

    #pragma unroll
    for (int c = 0; c < 2; c++) {
        #pragma unroll
        for (int i = 0; i < 7; i++) {
            const int t = i * 16 + tg;
            if (t >= c * CHUNK && t < c * CHUNK + CHUNK && t < TMAX) {
                const int r = t - c * CHUNK;
                float4 c0, c1;
                c0.x = acc[i][0] + bb[0]; c0.y = acc[i][1] + bb[1];
                c0.z = acc[i][2] + bb[2]; c0.w = acc[i][3] + bb[3];
                c1.x = acc[i][4] + bb[4]; c1.y = acc[i][5] + bb[5];
                c1.z = acc[i][6] + bb[6]; c1.w = acc[i][7] + bb[7];
                *(float4*)(smem + r * CS + 4 * ug)      = c0;
                *(float4*)(smem + r * CS + 64 + 4 * ug) = c1;
            }
        }
        __syncthreads();
        if (tid < UN) {
#pragma clang fp contract(off)
            // rounding matches numpy elementwise exactly:
            // v = 0.25*v + round(0.75*c); spike = v > 1.0; v -= spike.
            for (int r = 0; r < CHUNK; r++) {
                float cval = smem[r * CS + tid];
                v = 0.25f * v + 0.75f * cval;
                float s = (v > 1.0f) ? 1.0f : 0.0f;
                v -= s;
                cnt += s;
                sp[(size_t)(c * CHUNK + r) * U] = s;
            }
        }
        __syncthreads();   // scan done before chunk 1 overwrites Cs
    }
    if (tid < UN) counts[(size_t)b * U + u0 + tid] = cnt;
}

extern "C" void kernel_launch(void* const* d_in, const int* in_sizes, int n_in,
                              void* d_out, int out_size, void* d_ws, size_t ws_size,
                              hipStream_t stream) {
    const float* x    = (const float*)d_in[0];  // [B,T,F]
    const float* kern = (const float*)d_in[1];  // [F,U]
    const float* bias = (const float*)d_in[2];  // [U]
    float* out = (float*)d_out;

    const int U = in_sizes[2];                 // 1024
    const int F = in_sizes[1] / U;             // 1024
    const int R = in_sizes[0] / F;             // B*T = 25600
    const int B = out_size / U - R;            // 256
    const int T = R / B;                       // 100

    float* spikes = out;
    float* counts = out + (size_t)R * U;

    dim3 grid(U / UN, B);                      // (8, 256)
    fused_snn<<<grid, 256, 0, stream>>>(x, kern, bias, spikes, counts,
                                        B, T, F, U);
}